// Round 1
// baseline (25.988 us; speedup 1.0000x reference)
//
#include <hip/hip_runtime.h>
#include <math.h>

#define NN 1536
#define CC 64

__device__ __forceinline__ float wredsum(float v) {
#pragma unroll
    for (int off = 32; off > 0; off >>= 1) v += __shfl_xor(v, off, 64);
    return v;
}

// b2[j] = ||x_j||^2 ; one wave per node j
__global__ void b2_kernel(const float* __restrict__ x, float* __restrict__ b2) {
    int wave = (blockIdx.x * blockDim.x + threadIdx.x) >> 6;
    int lane = threadIdx.x & 63;
    if (wave >= NN) return;
    float v = x[wave * CC + lane];
    float s = wredsum(v * v);
    if (lane == 0) b2[wave] = s;
}

// One block (4 waves) per row i. Lanes map to channels (and to j within an
// adj chunk for the sparsity scan). All per-pair math reduces to scalars
// derived from (dot_ij, a2_i, b2_j).
__launch_bounds__(256)
__global__ void hmp_kernel(const float* __restrict__ x,
                           const float* __restrict__ adj,
                           const float* __restrict__ W,
                           const float* __restrict__ bias,
                           const float* __restrict__ b2arr,
                           float* __restrict__ out) {
    const int i = blockIdx.x;
    const int w = threadIdx.x >> 6;
    const int lane = threadIdx.x & 63;

    __shared__ float s_acc[4][CC];
    __shared__ float s_coefA[4];
    __shared__ float s_deg[4];

    const float xi = x[i * CC + lane];
    const float a2 = wredsum(xi * xi);
    const float B = 1.0f - a2;   // 2/(sqrt_c*lam_x) with c=1 (a2 < 1 here)

    float acc = 0.0f;     // per-lane channel accumulation of g*B*x_j[lane]
    float coefA = 0.0f;   // wave-uniform: sum of g*A (multiplies -x_i)
    float degl = 0.0f;

    const float* adjrow = adj + (size_t)i * NN;
    for (int ch = w; ch < NN / 64; ch += 4) {
        const int j0 = ch * 64;
        const float adjv = adjrow[j0 + lane];
        degl += adjv;
        unsigned long long m = __ballot(adjv != 0.0f);
        while (m) {
            const int jj = __builtin_ctzll(m);
            m &= m - 1;
            const int j = j0 + jj;
            const float aval = __shfl(adjv, jj, 64);        // adj value (uniform)
            const float xj = x[j * CC + lane];              // coalesced 256B
            const float dot = wredsum(xi * xj);             // uniform after reduce
            const float b2 = b2arr[j];                      // broadcast load
            const float A = 1.0f - 2.0f * dot + b2;
            float D = fmaxf(1.0f - 2.0f * dot + a2 * b2, 1e-15f);
            const float rD = 1.0f / D;
            // ||sub||^2 = (A^2*a2 - 2AB*dot + B^2*b2)/D^2
            const float num = fmaxf(A * A * a2 - 2.0f * A * B * dot + B * B * b2, 0.0f);
            const float sub2 = num * rD * rD;
            const float sn = fmaxf(sqrtf(sub2), 1e-15f);
            const float z = fminf(sn, 1.0f - 1e-5f);
            const float ath = 0.5f * logf((1.0f + z) / (1.0f - z));  // artanh
            const float g = aval * B * (ath / sn) * rD;
            coefA += g * A;
            acc = fmaf(g * B, xj, acc);
        }
    }

    degl = wredsum(degl);
    s_acc[w][lane] = acc;
    if (lane == 0) { s_coefA[w] = coefA; s_deg[w] = degl; }
    __syncthreads();

    if (w == 0) {
        float acct = s_acc[0][lane] + s_acc[1][lane] + s_acc[2][lane] + s_acc[3][lane];
        const float coefAt = s_coefA[0] + s_coefA[1] + s_coefA[2] + s_coefA[3];
        float deg = fmaxf(s_deg[0] + s_deg[1] + s_deg[2] + s_deg[3], 1e-8f);
        const float agg = (acct - xi * coefAt) / deg;       // agg_i[lane]

        // transformed[o=lane] = sum_c agg[c] * W[c][o] + bias[o]
        float t = bias[lane];
#pragma unroll
        for (int c0 = 0; c0 < CC; ++c0) {
            t = fmaf(__shfl(agg, c0, 64), W[c0 * CC + lane], t);
        }
        // expmap at origin: tanh(||t||) * t / ||t||
        const float vn2 = wredsum(t * t);
        const float vn = fmaxf(sqrtf(vn2), 1e-15f);
        const float f = tanhf(vn) / vn;
        out[i * CC + lane] = f * t;
    }
}

extern "C" void kernel_launch(void* const* d_in, const int* in_sizes, int n_in,
                              void* d_out, int out_size, void* d_ws, size_t ws_size,
                              hipStream_t stream) {
    const float* x    = (const float*)d_in[0];
    const float* adj  = (const float*)d_in[1];
    const float* W    = (const float*)d_in[2];
    const float* bias = (const float*)d_in[3];
    float* out = (float*)d_out;
    float* b2  = (float*)d_ws;   // 1536 floats

    b2_kernel<<<NN / 4, 256, 0, stream>>>(x, b2);
    hmp_kernel<<<NN, 256, 0, stream>>>(x, adj, W, bias, b2, out);
}

// Round 2
// 16.459 us; speedup vs baseline: 1.5790x; 1.5790x over previous
//
#include <hip/hip_runtime.h>
#include <math.h>

#define NN 1536
#define CC 64
#define NWAVES 8
#define NCHUNK (NN / 64)       // 24
#define CPW (NCHUNK / NWAVES)  // 3

__device__ __forceinline__ float wredsum64(float v) {
#pragma unroll
    for (int off = 32; off > 0; off >>= 1) v += __shfl_xor(v, off, 64);
    return v;
}

// Single fused kernel. One block (8 waves) per row i.
// Within a wave: lanes split into 4 groups of 16; each group handles one
// neighbor pair j at a time; each lane holds a float4 slice of the 64
// channels. b2_j is computed on the fly (packed with the dot reduce), so no
// separate pre-kernel is needed.
__launch_bounds__(512)
__global__ void hmp_kernel(const float* __restrict__ x,
                           const float* __restrict__ adj,
                           const float* __restrict__ W,
                           const float* __restrict__ bias,
                           float* __restrict__ out) {
    const int i = blockIdx.x;
    const int w = threadIdx.x >> 6;
    const int lane = threadIdx.x & 63;
    const int sub = lane & 15;   // which float4 slice of the 64 channels
    const int grp = lane >> 4;   // pair slot 0..3

    __shared__ float s_acc[NWAVES][CC];
    __shared__ float s_coefA[NWAVES];
    __shared__ float s_deg[NWAVES];

    const float4 xi4 = reinterpret_cast<const float4*>(x + (size_t)i * CC)[sub];

    // a2 = ||x_i||^2 : 16-lane reduce (replicated across the 4 groups)
    float a2 = xi4.x * xi4.x + xi4.y * xi4.y + xi4.z * xi4.z + xi4.w * xi4.w;
#pragma unroll
    for (int off = 1; off < 16; off <<= 1) a2 += __shfl_xor(a2, off, 64);
    const float B = 1.0f - a2;

    // prefetch this wave's adj chunks (independent loads, one latency)
    const float* adjrow = adj + (size_t)i * NN;
    float adjv[CPW];
#pragma unroll
    for (int q = 0; q < CPW; ++q) adjv[q] = adjrow[(w * CPW + q) * 64 + lane];

    float accx = 0.0f, accy = 0.0f, accz = 0.0f, accw = 0.0f;
    float coefA = 0.0f, degl = 0.0f;

#pragma unroll
    for (int q = 0; q < CPW; ++q) {
        const float av = adjv[q];
        degl += av;
        unsigned long long m = __ballot(av != 0.0f);
        const int j0 = (w * CPW + q) * 64;
        while (m) {
            // extract up to 4 set bits (uniform across lanes)
            int jj0 = __builtin_ctzll(m); m &= m - 1;
            int jj1 = -1, jj2 = -1, jj3 = -1;
            if (m) { jj1 = __builtin_ctzll(m); m &= m - 1; }
            if (m) { jj2 = __builtin_ctzll(m); m &= m - 1; }
            if (m) { jj3 = __builtin_ctzll(m); m &= m - 1; }
            const int myj = (grp == 0) ? jj0 : (grp == 1) ? jj1 : (grp == 2) ? jj2 : jj3;
            const bool valid = myj >= 0;
            const int sj = valid ? myj : jj0;          // safe duplicate index
            float mya = __shfl(av, sj, 64);            // adj value for this pair
            if (!valid) mya = 0.0f;                    // kills the contribution

            const float4 xj4 =
                reinterpret_cast<const float4*>(x + (size_t)(j0 + sj) * CC)[sub];
            float pd = xi4.x * xj4.x + xi4.y * xj4.y + xi4.z * xj4.z + xi4.w * xj4.w;
            float pb = xj4.x * xj4.x + xj4.y * xj4.y + xj4.z * xj4.z + xj4.w * xj4.w;
#pragma unroll
            for (int off = 1; off < 16; off <<= 1) {   // packed 16-lane reduce
                pd += __shfl_xor(pd, off, 64);
                pb += __shfl_xor(pb, off, 64);
            }
            const float dot = pd, b2 = pb;
            const float A = 1.0f - 2.0f * dot + b2;
            const float D = fmaxf(1.0f - 2.0f * dot + a2 * b2, 1e-15f);
            const float rD = 1.0f / D;
            const float num = fmaxf(A * A * a2 - 2.0f * A * B * dot + B * B * b2, 0.0f);
            const float sub2 = num * rD * rD;
            const float sn = fmaxf(sqrtf(sub2), 1e-15f);
            const float z = fminf(sn, 1.0f - 1e-5f);
            const float ath = 0.5f * logf((1.0f + z) / (1.0f - z));  // artanh
            const float g = mya * B * (ath / sn) * rD;
            coefA += g * A;
            const float gB = g * B;
            accx = fmaf(gB, xj4.x, accx);
            accy = fmaf(gB, xj4.y, accy);
            accz = fmaf(gB, xj4.z, accz);
            accw = fmaf(gB, xj4.w, accw);
        }
    }

    // sum the 4 groups' partials (each uniform within its 16-lane group)
#pragma unroll
    for (int off = 16; off < 64; off <<= 1) {
        accx += __shfl_xor(accx, off, 64);
        accy += __shfl_xor(accy, off, 64);
        accz += __shfl_xor(accz, off, 64);
        accw += __shfl_xor(accw, off, 64);
        coefA += __shfl_xor(coefA, off, 64);
    }
    degl = wredsum64(degl);

    if (lane < 16)
        reinterpret_cast<float4*>(s_acc[w])[sub] = make_float4(accx, accy, accz, accw);
    if (lane == 0) { s_coefA[w] = coefA; s_deg[w] = degl; }
    __syncthreads();

    if (w == 0) {
        float acct = 0.0f, coefAt = 0.0f, deg = 0.0f;
#pragma unroll
        for (int q = 0; q < NWAVES; ++q) {
            acct += s_acc[q][lane];
            coefAt += s_coefA[q];
            deg += s_deg[q];
        }
        deg = fmaxf(deg, 1e-8f);
        const float xl = x[(size_t)i * CC + lane];
        const float agg = (acct - xl * coefAt) / deg;   // agg_i[channel=lane]

        // transformed[o=lane] = sum_c agg[c] * W[c][o] + bias[o]
        float t = bias[lane];
#pragma unroll
        for (int c0 = 0; c0 < CC; ++c0) {
            t = fmaf(__shfl(agg, c0, 64), W[c0 * CC + lane], t);
        }
        // expmap at origin: tanh(||t||) * t / ||t||
        const float vn2 = wredsum64(t * t);
        const float vn = fmaxf(sqrtf(vn2), 1e-15f);
        const float f = tanhf(vn) / vn;
        out[(size_t)i * CC + lane] = f * t;
    }
}

extern "C" void kernel_launch(void* const* d_in, const int* in_sizes, int n_in,
                              void* d_out, int out_size, void* d_ws, size_t ws_size,
                              hipStream_t stream) {
    const float* x    = (const float*)d_in[0];
    const float* adj  = (const float*)d_in[1];
    const float* W    = (const float*)d_in[2];
    const float* bias = (const float*)d_in[3];
    float* out = (float*)d_out;

    hmp_kernel<<<NN, 512, 0, stream>>>(x, adj, W, bias, out);
}

// Round 3
// 12.438 us; speedup vs baseline: 2.0894x; 1.3233x over previous
//
#include <hip/hip_runtime.h>
#include <math.h>

#define NN 1536
#define CC 64
#define MAXP 160   // max neighbors per row we queue (mean ~31, safe bound)

__device__ __forceinline__ float wredsum64(float v) {
#pragma unroll
    for (int off = 32; off > 0; off >>= 1) v += __shfl_xor(v, off, 64);
    return v;
}

// One block (256 thr = 4 waves = 16 groups of 16 lanes) per row i.
// Phase A: scan adj row (float4), queue nonzero (j, a_ij) in LDS.
// Phase B: groups process pairs; lane holds a float4 slice of 64 channels.
// Phase C: block-reduce partials -> agg_i.
// Phase D: 64x64 GEMV split over 4 waves + expmap_0 by wave 0.
__launch_bounds__(256, 6)
__global__ void hmp_kernel(const float* __restrict__ x,
                           const float* __restrict__ adj,
                           const float* __restrict__ W,
                           const float* __restrict__ bias,
                           float* __restrict__ out) {
    const int i = blockIdx.x;
    const int tid = threadIdx.x;
    const int w = tid >> 6;
    const int lane = tid & 63;
    const int sub = tid & 15;   // float4 slice within 64 channels
    const int g = tid >> 4;     // group id 0..15

    __shared__ int s_np;
    __shared__ int s_q[MAXP];
    __shared__ float s_qa[MAXP];
    __shared__ float s_part[16][CC];
    __shared__ float s_coefA[16];
    __shared__ float s_deg[4];
    __shared__ float s_agg[CC];
    __shared__ float s_t[4][CC];

    if (tid == 0) s_np = 0;

    // long-latency loads issued first
    const float4 xi4 = reinterpret_cast<const float4*>(x + (size_t)i * CC)[sub];
    const float4* arow4 = reinterpret_cast<const float4*>(adj + (size_t)i * NN);
    const float4 a0 = arow4[tid];                       // j = 4*tid .. +3
    float4 a1 = make_float4(0.f, 0.f, 0.f, 0.f);
    if (tid < 128) a1 = arow4[256 + tid];               // j = 1024 + 4*tid ..

    float a2 = xi4.x * xi4.x + xi4.y * xi4.y + xi4.z * xi4.z + xi4.w * xi4.w;
#pragma unroll
    for (int off = 1; off < 16; off <<= 1) a2 += __shfl_xor(a2, off, 64);
    const float B = 1.0f - a2;

    float degl = a0.x + a0.y + a0.z + a0.w + a1.x + a1.y + a1.z + a1.w;
    degl = wredsum64(degl);
    if (lane == 0) s_deg[w] = degl;

    __syncthreads();   // s_np initialized, s_deg visible later

    {
        const float va[8] = {a0.x, a0.y, a0.z, a0.w, a1.x, a1.y, a1.z, a1.w};
#pragma unroll
        for (int k = 0; k < 8; ++k) {
            const float v = va[k];
            if (v != 0.0f) {
                const int p = atomicAdd(&s_np, 1);
                if (p < MAXP) {
                    s_q[p] = (k < 4) ? (4 * tid + k) : (1024 + 4 * tid + (k - 4));
                    s_qa[p] = v;
                }
            }
        }
    }
    __syncthreads();
    const int np = min(s_np, MAXP);

    // Phase B: each 16-lane group takes pairs g, g+16, ...
    float accx = 0.f, accy = 0.f, accz = 0.f, accw = 0.f, coefA = 0.f;
    for (int p = g; p < np; p += 16) {
        const int j = s_q[p];
        const float aval = s_qa[p];
        const float4 xj4 = reinterpret_cast<const float4*>(x + (size_t)j * CC)[sub];
        float pd = xi4.x * xj4.x + xi4.y * xj4.y + xi4.z * xj4.z + xi4.w * xj4.w;
        float pb = xj4.x * xj4.x + xj4.y * xj4.y + xj4.z * xj4.z + xj4.w * xj4.w;
#pragma unroll
        for (int off = 1; off < 16; off <<= 1) {   // packed 16-lane reduce
            pd += __shfl_xor(pd, off, 64);
            pb += __shfl_xor(pb, off, 64);
        }
        const float dot = pd, b2 = pb;
        const float A = 1.0f - 2.0f * dot + b2;
        const float D = fmaxf(1.0f - 2.0f * dot + a2 * b2, 1e-15f);
        const float rD = 1.0f / D;
        const float num = fmaxf(A * A * a2 - 2.0f * A * B * dot + B * B * b2, 0.0f);
        const float sub2 = num * rD * rD;
        const float sn = fmaxf(sqrtf(sub2), 1e-15f);
        const float z = fminf(sn, 1.0f - 1e-5f);
        const float ath = 0.5f * logf((1.0f + z) / (1.0f - z));   // artanh
        const float gg = aval * B * (ath / sn) * rD;
        coefA = fmaf(gg, A, coefA);
        const float gB = gg * B;
        accx = fmaf(gB, xj4.x, accx);
        accy = fmaf(gB, xj4.y, accy);
        accz = fmaf(gB, xj4.z, accz);
        accw = fmaf(gB, xj4.w, accw);
    }
    reinterpret_cast<float4*>(s_part[g])[sub] = make_float4(accx, accy, accz, accw);
    if (sub == 0) s_coefA[g] = coefA;
    __syncthreads();

    // Phase C: wave 0 combines 16 group partials -> agg
    if (w == 0) {
        float acct = 0.f, coefAt = 0.f;
#pragma unroll
        for (int q = 0; q < 16; ++q) {
            acct += s_part[q][lane];
            coefAt += s_coefA[q];
        }
        const float deg = fmaxf(s_deg[0] + s_deg[1] + s_deg[2] + s_deg[3], 1e-8f);
        const float xl = x[(size_t)i * CC + lane];
        s_agg[lane] = (acct - xl * coefAt) / deg;
    }
    __syncthreads();

    // Phase D: GEMV split over 4 waves (wave w handles c in [16w,16w+16))
    {
        float t = 0.f;
        const int c0 = w * 16;
#pragma unroll
        for (int k = 0; k < 16; ++k) {
            t = fmaf(s_agg[c0 + k], W[(c0 + k) * CC + lane], t);
        }
        s_t[w][lane] = t;
    }
    __syncthreads();

    if (w == 0) {
        float t = bias[lane] + s_t[0][lane] + s_t[1][lane] + s_t[2][lane] + s_t[3][lane];
        const float vn2 = wredsum64(t * t);
        const float vn = fmaxf(sqrtf(vn2), 1e-15f);
        const float f = tanhf(vn) / vn;
        out[(size_t)i * CC + lane] = f * t;
    }
}

extern "C" void kernel_launch(void* const* d_in, const int* in_sizes, int n_in,
                              void* d_out, int out_size, void* d_ws, size_t ws_size,
                              hipStream_t stream) {
    const float* x    = (const float*)d_in[0];
    const float* adj  = (const float*)d_in[1];
    const float* W    = (const float*)d_in[2];
    const float* bias = (const float*)d_in[3];
    float* out = (float*)d_out;

    hmp_kernel<<<NN, 256, 0, stream>>>(x, adj, W, bias, out);
}